// Round 3
// baseline (12997.809 us; speedup 1.0000x reference)
//
#include <hip/hip_runtime.h>
#include <hip/hip_fp16.h>
#include <stdint.h>

#define S_LEN 512
#define HD 1280
#define GD 5120   // 4*C
#define VOC 32000

typedef __attribute__((ext_vector_type(8))) short short8;
typedef __attribute__((ext_vector_type(8))) _Float16 half8;
typedef __attribute__((ext_vector_type(4))) float floatx4;
typedef __attribute__((ext_vector_type(2))) _Float16 halfx2;
typedef __attribute__((ext_vector_type(4))) _Float16 halfx4;

static __device__ __forceinline__ unsigned short f2h(float f) {
  return __builtin_bit_cast(unsigned short, (_Float16)f);
}
static __device__ __forceinline__ float h2f(unsigned short h) {
  return (float)__builtin_bit_cast(_Float16, h);
}
static __device__ __forceinline__ float tanhf_fast(float x) {
  float xc = fminf(fmaxf(x, -15.f), 15.f);
  float e = __expf(2.f * xc);
  return (e - 1.f) / (e + 1.f);
}
#if __has_builtin(__builtin_amdgcn_fdot2)
static __device__ __forceinline__ float fdot2(halfx2 a, halfx2 b, float c) {
  return __builtin_amdgcn_fdot2(a, b, c, false);
}
#else
static __device__ __forceinline__ float fdot2(halfx2 a, halfx2 b, float c) {
  return c + (float)a[0]*(float)b[0] + (float)a[1]*(float)b[1];
}
#endif

// ---------------------------------------------------------------------------
// Transpose + fp32->f16 convert: in (R x C) fp32 row-major -> out (C x R) f16
// ---------------------------------------------------------------------------
__global__ __launch_bounds__(256)
void transpose_cvt(const float* __restrict__ in, unsigned short* __restrict__ out,
                   int R, int C)
{
  __shared__ float tile[32][33];
  const int c0 = blockIdx.x * 32;
  const int r0 = blockIdx.y * 32;
  const int tx = threadIdx.x & 31;
  const int ty = threadIdx.x >> 5;   // 0..7
#pragma unroll
  for (int p = 0; p < 4; p++) {
    int rl = ty + p * 8;
    tile[rl][tx] = in[(size_t)(r0 + rl) * C + c0 + tx];
  }
  __syncthreads();
#pragma unroll
  for (int p = 0; p < 4; p++) {
    int cl = ty + p * 8;
    out[(size_t)(c0 + cl) * R + r0 + tx] = f2h(tile[tx][cl]);
  }
}

// ---------------------------------------------------------------------------
// Generic MFMA GEMM (fp16 inputs, fp32 accum):
//   C(MxN) = A(MxK) * B(KxN) [B given as B^T (NxK) f16]
// CMODE: 0 = xp   (fp32 out, +bias, A rows are (b,s); out row (s',b), rev opt)
//        1 = WfT  (f16 out, transposed write out[col*M + row])
//        2 = Hcat (f16 out, A rows are (t,b); out row (b,s'), rev, +resid opt)
//        3 = logits (fp32 out, +bias, identity rows)
// AFP32: A is fp32 (converted to f16 during staging)
// ---------------------------------------------------------------------------
template<int AFP32, int CMODE>
__global__ __launch_bounds__(256, 2)
void gemm_k(const void* __restrict__ Ap, const unsigned short* __restrict__ BTp,
            void* __restrict__ Cp, const float* __restrict__ bias,
            const unsigned short* __restrict__ resid,
            int M, int N, int K, int rev)
{
  __shared__ __align__(16) short As[128 * 32];
  __shared__ __align__(16) short Bs[128 * 32];
  const int tid  = threadIdx.x;
  const int row0 = blockIdx.y * 128;
  const int col0 = blockIdx.x * 128;
  const int lane = tid & 63;
  const int wid  = tid >> 6;
  const int wrow = (wid >> 1) * 64;
  const int wcol = (wid & 1) * 64;
  const int lr   = lane & 15;
  const int gg   = lane >> 4;

  floatx4 acc[4][4];
#pragma unroll
  for (int m = 0; m < 4; m++)
#pragma unroll
    for (int n = 0; n < 4; n++)
      acc[m][n] = (floatx4)0.0f;

  for (int k0 = 0; k0 < K; k0 += 32) {
    __syncthreads();
#pragma unroll
    for (int p = 0; p < 2; p++) {
      int idx = p * 256 + tid;
      int r = idx >> 2, c = idx & 3;
      short8 va;
      if constexpr (AFP32) {
        const float* src = (const float*)Ap + (size_t)(row0 + r) * K + k0 + c * 8;
        floatx4 f0 = *(const floatx4*)src;
        floatx4 f1 = *(const floatx4*)(src + 4);
        va[0] = (short)f2h(f0[0]); va[1] = (short)f2h(f0[1]);
        va[2] = (short)f2h(f0[2]); va[3] = (short)f2h(f0[3]);
        va[4] = (short)f2h(f1[0]); va[5] = (short)f2h(f1[1]);
        va[6] = (short)f2h(f1[2]); va[7] = (short)f2h(f1[3]);
      } else {
        va = *(const short8*)((const unsigned short*)Ap + (size_t)(row0 + r) * K + k0 + c * 8);
      }
      *(short8*)&As[r * 32 + ((c ^ (r & 3)) * 8)] = va;
      short8 vb = *(const short8*)(BTp + (size_t)(col0 + r) * K + k0 + c * 8);
      *(short8*)&Bs[r * 32 + ((c ^ (r & 3)) * 8)] = vb;
    }
    __syncthreads();
    short8 af[4], bfv[4];
#pragma unroll
    for (int m = 0; m < 4; m++) {
      int r = wrow + m * 16 + lr;
      af[m] = *(const short8*)&As[r * 32 + ((gg ^ (r & 3)) * 8)];
    }
#pragma unroll
    for (int n = 0; n < 4; n++) {
      int c = wcol + n * 16 + lr;
      bfv[n] = *(const short8*)&Bs[c * 32 + ((gg ^ (c & 3)) * 8)];
    }
#pragma unroll
    for (int m = 0; m < 4; m++)
#pragma unroll
      for (int n = 0; n < 4; n++)
        acc[m][n] = __builtin_amdgcn_mfma_f32_16x16x32_f16(
            __builtin_bit_cast(half8, af[m]), __builtin_bit_cast(half8, bfv[n]),
            acc[m][n], 0, 0, 0);
  }

  // Epilogue. Verified C layout: col = lane&15, row = 4*(lane>>4) + i.
#pragma unroll
  for (int m = 0; m < 4; m++) {
    int rbase = row0 + wrow + m * 16 + 4 * gg;
#pragma unroll
    for (int n = 0; n < 4; n++) {
      int col = col0 + wcol + n * 16 + lr;
      if constexpr (CMODE == 1) {
        halfx4 t4;
#pragma unroll
        for (int i = 0; i < 4; i++) t4[i] = (_Float16)acc[m][n][i];
        *(halfx4*)((_Float16*)Cp + (size_t)col * M + rbase) = t4;
      } else if constexpr (CMODE == 0) {
        float bv = bias[col];
#pragma unroll
        for (int i = 0; i < 4; i++) {
          int r = rbase + i;
          int b = r >> 9, s = r & 511;          // A rows are (b,s)
          int so = rev ? (511 - s) : s;
          ((float*)Cp)[(size_t)((so << 1) | b) * GD + col] = acc[m][n][i] + bv;
        }
      } else if constexpr (CMODE == 2) {
#pragma unroll
        for (int i = 0; i < 4; i++) {
          int r = rbase + i;
          int t = r >> 1, b = r & 1;            // A rows (Pout) are (t,b)
          int s = rev ? (511 - t) : t;
          size_t o = (size_t)((b << 9) | s) * HD + col;
          float v = acc[m][n][i];
          if (resid) v += h2f(resid[o]);
          ((unsigned short*)Cp)[o] = f2h(v);
        }
      } else {
        float bv = bias[col];
#pragma unroll
        for (int i = 0; i < 4; i++)
          ((float*)Cp)[(size_t)(rbase + i) * N + col] = acc[m][n][i] + bv;
      }
    }
  }
}

// ---------------------------------------------------------------------------
// Persistent LSTM scan (one layer, both directions).
// 256 WGs: WG = (dir = bid&1, g = bid>>1). WG owns j in [g*10, g*10+10) i.e.
// gate columns {q*1280 + j} for q=0..3 (40 cols). Wf^T slice held in registers
// (f16). Per step: g = xp[t] + p(t-1) @ Wf  (p broadcast from global, f16),
// cell update by 20 owner threads, p' written to double-buffered global buf,
// per-direction barrier via monotone arrival counter (agent scope, release).
// ---------------------------------------------------------------------------
__global__ __launch_bounds__(256, 1)
void lstm_scan(const _Float16* __restrict__ wfT,   // [2][GD][HD] this layer
               const float* __restrict__ xp,       // [2][1024][GD]
               unsigned short* __restrict__ Pout,  // [2][1024][HD] f16
               unsigned int* __restrict__ pbuf,    // [2][2][2][640] u32 (f16 pairs)
               unsigned int* __restrict__ ctr)     // [2]
{
  const int dir = blockIdx.x & 1;
  const int g   = blockIdx.x >> 1;    // 0..127
  const int jbase = g * 10;
  const int tid = threadIdx.x;
  const int q   = tid & 3;            // gate
  const int kq  = tid >> 2;           // 0..63 k-slice
  const int k2  = kq * 10;            // u32 offset (20 f16 per slice)

  __shared__ float part[80][68];
  __shared__ float gvals[40][2];

  // load weight slice into registers: 10 cols x 20 f16
  unsigned int wreg[10][10];
#pragma unroll
  for (int c = 0; c < 10; c++) {
    const unsigned int* src =
      (const unsigned int*)(wfT + ((size_t)dir * GD + q * HD + jbase + c) * HD) + k2;
#pragma unroll
    for (int kk = 0; kk < 10; kk += 2) {
      uint2 u = *(const uint2*)(src + kk);
      wreg[c][kk] = u.x; wreg[c][kk + 1] = u.y;
    }
  }

  unsigned int* pb0 = pbuf + (dir * 2 + 0) * 2 * 640;
  unsigned int* pb1 = pbuf + (dir * 2 + 1) * 2 * 640;

  const bool isRed = tid < 80;
  const int rcl = tid >> 1, rb = tid & 1;
  const int colg = (rcl / 10) * HD + jbase + (rcl % 10);

  const bool isOwn = tid < 20;
  const int oj = tid >> 1, ob = tid & 1;
  float cst = 0.f;

  for (int t = 0; t < S_LEN; t++) {
    if (t > 0) {
      if (tid == 0) {
        const unsigned target = (unsigned)t * 128u;
        while (__hip_atomic_load(ctr + dir, __ATOMIC_ACQUIRE, __HIP_MEMORY_SCOPE_AGENT) < target)
          __builtin_amdgcn_s_sleep(2);
      }
      __syncthreads();
    }
    float xpv = 0.f;
    if (isRed) xpv = xp[((size_t)dir * 1024 + t * 2 + rb) * GD + colg];

    unsigned int* pr = (t & 1) ? pb1 : pb0;
    unsigned int p0[10], p1[10];
#pragma unroll
    for (int kk = 0; kk < 10; kk++) {
      p0[kk] = __hip_atomic_load(pr + k2 + kk,       __ATOMIC_RELAXED, __HIP_MEMORY_SCOPE_AGENT);
      p1[kk] = __hip_atomic_load(pr + 640 + k2 + kk, __ATOMIC_RELAXED, __HIP_MEMORY_SCOPE_AGENT);
    }
    float acc0[10], acc1[10];
#pragma unroll
    for (int c = 0; c < 10; c++) { acc0[c] = 0.f; acc1[c] = 0.f; }
#pragma unroll
    for (int c = 0; c < 10; c++)
#pragma unroll
      for (int kk = 0; kk < 10; kk++) {
        halfx2 wv = __builtin_bit_cast(halfx2, wreg[c][kk]);
        acc0[c] = fdot2(__builtin_bit_cast(halfx2, p0[kk]), wv, acc0[c]);
        acc1[c] = fdot2(__builtin_bit_cast(halfx2, p1[kk]), wv, acc1[c]);
      }
#pragma unroll
    for (int c = 0; c < 10; c++) {
      part[(q * 10 + c) * 2 + 0][kq] = acc0[c];
      part[(q * 10 + c) * 2 + 1][kq] = acc1[c];
    }
    __syncthreads();
    if (isRed) {
      float s = 0.f;
#pragma unroll
      for (int j4 = 0; j4 < 16; j4++) {
        floatx4 v = *(const floatx4*)&part[tid][j4 * 4];
        s += (v[0] + v[1]) + (v[2] + v[3]);
      }
      gvals[rcl][rb] = s + xpv;
    }
    __syncthreads();
    if (isOwn) {
      float gi = gvals[oj][ob];
      float gf = gvals[10 + oj][ob];
      float gz = gvals[20 + oj][ob];
      float go = gvals[30 + oj][ob];
      float si = 1.f / (1.f + __expf(-gi));
      float sf = 1.f / (1.f + __expf(-gf));
      float so = 1.f / (1.f + __expf(-go));
      float tz = tanhf_fast(gz);
      cst = si * tz + sf * cst;
      float pv = so * tanhf_fast(cst);
      unsigned int* pw = (t & 1) ? pb0 : pb1;   // write buf (t+1)&1
      ((unsigned short*)pw)[ob * HD + jbase + oj] = f2h(pv);
      Pout[((size_t)dir * 1024 + t * 2 + ob) * HD + jbase + oj] = f2h(pv);
    }
    __syncthreads();   // drains owners' stores before release add
    if (tid == 0) {
      __hip_atomic_fetch_add(ctr + dir, 1u, __ATOMIC_RELEASE, __HIP_MEMORY_SCOPE_AGENT);
    }
  }
}

// ---------------------------------------------------------------------------
extern "C" void kernel_launch(void* const* d_in, const int* in_sizes, int n_in,
                              void* d_out, int out_size, void* d_ws, size_t ws_size,
                              hipStream_t stream)
{
  char* W = (char*)d_ws;
  // workspace layout (bytes) — all 2-byte planes are f16 now
  const size_t WS_T  = 0;                    // Ws^T f16 [4][GD][HD]    52,428,800
  const size_t WI_T  = 52428800;             // Wi^T f16 [4][GD][HD]    52,428,800
  const size_t WP_T  = 104857600;            // Wp^T f16 [4][HD][HD]    13,107,200
  const size_t WF_T  = 117964800;            // Wf^T f16 [4][GD][HD]    52,428,800
  const size_t HCAT  = 170393600;            // f16 [4096][HD]          10,485,760
  const size_t P_O   = 180879360;            // f16 [2][1024][HD]        5,242,880
  const size_t XP_O  = 186122240;            // f32 [2][1024][GD]       41,943,040
  const size_t PB_O  = 228065280;            // u32 [2][2][2][2][640]       40,960
  const size_t CTR_O = 228106240;            //                                256
  const size_t NEED  = 228106496;
  const size_t WLIN_T = 0;                   // alias over WS_T/WI_T (dead by then)
  if (ws_size < NEED) return;

  const float* x    = (const float*)d_in[0];
  const float* Wi_f = (const float*)d_in[1];
  const float* Ws_f = (const float*)d_in[2];
  const float* b_f  = (const float*)d_in[3];
  const float* Wp_f = (const float*)d_in[4];
  const float* Wi_b = (const float*)d_in[5];
  const float* Ws_b = (const float*)d_in[6];
  const float* b_b  = (const float*)d_in[7];
  const float* Wp_b = (const float*)d_in[8];
  const float* Wlin = (const float*)d_in[9];
  const float* blin = (const float*)d_in[10];

  hipMemsetAsync(W + PB_O, 0, 40960 + 256, stream);

  // weight transposes (+f16)
  for (int l = 0; l < 2; l++)
    for (int d = 0; d < 2; d++) {
      int ld = l * 2 + d;
      const float* ws_src = (d ? Ws_b : Ws_f) + (size_t)l * HD * GD;
      const float* wi_src = (d ? Wi_b : Wi_f) + (size_t)l * HD * GD;
      const float* wp_src = (d ? Wp_b : Wp_f) + (size_t)l * HD * HD;
      transpose_cvt<<<dim3(GD / 32, HD / 32), 256, 0, stream>>>(
        ws_src, (unsigned short*)(W + WS_T) + (size_t)ld * GD * HD, HD, GD);
      transpose_cvt<<<dim3(GD / 32, HD / 32), 256, 0, stream>>>(
        wi_src, (unsigned short*)(W + WI_T) + (size_t)ld * GD * HD, HD, GD);
      transpose_cvt<<<dim3(HD / 32, HD / 32), 256, 0, stream>>>(
        wp_src, (unsigned short*)(W + WP_T) + (size_t)ld * HD * HD, HD, HD);
    }

  // Wf = Wp @ Ws, written transposed as f16
  for (int l = 0; l < 2; l++)
    for (int d = 0; d < 2; d++) {
      int ld = l * 2 + d;
      const float* wp_src = (d ? Wp_b : Wp_f) + (size_t)l * HD * HD;
      gemm_k<1, 1><<<dim3(GD / 128, HD / 128), 256, 0, stream>>>(
        wp_src, (const unsigned short*)(W + WS_T) + (size_t)ld * GD * HD,
        (void*)((_Float16*)(W + WF_T) + (size_t)ld * GD * HD),
        nullptr, nullptr, HD, GD, HD, 0);
    }

  for (int l = 0; l < 2; l++) {
    // xp = in @ Wi + b  (time-reversed rows for bwd)
    for (int d = 0; d < 2; d++) {
      int ld = l * 2 + d;
      const float* bias = (d ? b_b : b_f) + (size_t)l * GD;
      if (l == 0) {
        gemm_k<1, 0><<<dim3(GD / 128, 1024 / 128), 256, 0, stream>>>(
          x, (const unsigned short*)(W + WI_T) + (size_t)ld * GD * HD,
          (void*)((float*)(W + XP_O) + (size_t)d * 1024 * GD),
          bias, nullptr, 1024, GD, HD, d);
      } else {
        const unsigned short* Ain =
          (const unsigned short*)(W + HCAT) + (size_t)(d * 2048 + (l - 1) * 1024) * HD;
        gemm_k<0, 0><<<dim3(GD / 128, 1024 / 128), 256, 0, stream>>>(
          Ain, (const unsigned short*)(W + WI_T) + (size_t)ld * GD * HD,
          (void*)((float*)(W + XP_O) + (size_t)d * 1024 * GD),
          bias, nullptr, 1024, GD, HD, d);
      }
    }
    if (l == 1) {
      // WS_T / WI_T regions are dead now: build W_lin^T in their place
      transpose_cvt<<<dim3(VOC / 32, HD / 32), 256, 0, stream>>>(
        Wlin, (unsigned short*)(W + WLIN_T), HD, VOC);
    }
    // recurrence
    lstm_scan<<<256, 256, 0, stream>>>(
      (const _Float16*)(W + WF_T) + (size_t)l * 2 * GD * HD,
      (const float*)(W + XP_O),
      (unsigned short*)(W + P_O),
      (unsigned int*)(W + PB_O) + (size_t)l * 2 * 2 * 2 * 640,
      (unsigned int*)(W + CTR_O) + l * 2);
    // ys = P @ Wp (+ residual for l>0) -> Hcat slice (b,s) rows
    for (int d = 0; d < 2; d++) {
      int ld = l * 2 + d;
      const unsigned short* resid = (l == 0) ? nullptr :
        (const unsigned short*)(W + HCAT) + (size_t)(d * 2048 + (l - 1) * 1024) * HD;
      gemm_k<0, 2><<<dim3(HD / 128, 1024 / 128), 256, 0, stream>>>(
        (const unsigned short*)(W + P_O) + (size_t)d * 1024 * HD,
        (const unsigned short*)(W + WP_T) + (size_t)ld * HD * HD,
        (void*)((unsigned short*)(W + HCAT) + (size_t)(d * 2048 + l * 1024) * HD),
        nullptr, resid, 1024, HD, HD, d);
    }
  }

  // logits = Hcat @ W_lin + b_lin  -> d_out (rows already in required order)
  gemm_k<0, 3><<<dim3(VOC / 128, 4096 / 128), 256, 0, stream>>>(
    (const unsigned short*)(W + HCAT), (const unsigned short*)(W + WLIN_T),
    d_out, blin, nullptr, 4096, VOC, HD, 0);
}